// Round 1
// baseline (8844.138 us; speedup 1.0000x reference)
//
#include <hip/hip_runtime.h>
#include <cfloat>
#include <cmath>

#define NN   20000
#define EE   640000
#define DIN  1546
#define DH   128
#define DFF  512
#define NLAYER 2

// ---------------------------------------------------------------------------
// Generic fp32 tiled GEMM: C[M,N] = act(A[M,K] @ B[K,N] + bias)
// act: 0 = none, 1 = relu, 2 = leaky_relu(0.01)
// 64x64 block tile, 256 threads, 4x4 per-thread micro-tile, BK=16.
// Scalar global loads (rows of A/B may be only 8B-aligned since 1546%4==2).
// ---------------------------------------------------------------------------
#define BM 64
#define BN 64
#define BK 16

__global__ __launch_bounds__(256) void gemm_f32(
    const float* __restrict__ A, const float* __restrict__ B,
    const float* __restrict__ bias, float* __restrict__ C,
    int M, int N, int K, int act)
{
  __shared__ float As[BK][BM + 4];  // As[k][m], pad to 68 (16B-aligned rows)
  __shared__ float Bs[BK][BN + 4];
  const int tid = threadIdx.x;
  const int bm = blockIdx.x * BM;
  const int bn = blockIdx.y * BN;
  const int tx = tid & 15, ty = tid >> 4;
  const int arow = tid >> 2, akq = (tid & 3) * 4;   // A tile: 64 rows x 16 k
  const int brow = tid >> 4, bcol = (tid & 15) * 4; // B tile: 16 k x 64 cols
  float acc[4][4] = {};

  for (int k0 = 0; k0 < K; k0 += BK) {
    const int ar = bm + arow;
    #pragma unroll
    for (int i = 0; i < 4; ++i) {
      int ak = k0 + akq + i;
      As[akq + i][arow] = (ar < M && ak < K) ? A[(size_t)ar * K + ak] : 0.f;
    }
    const int bk_ = k0 + brow;
    #pragma unroll
    for (int i = 0; i < 4; ++i) {
      int bc = bn + bcol + i;
      Bs[brow][bcol + i] = (bk_ < K && bc < N) ? B[(size_t)bk_ * N + bc] : 0.f;
    }
    __syncthreads();
    #pragma unroll
    for (int kk = 0; kk < BK; ++kk) {
      const float4 a = *(const float4*)&As[kk][ty * 4];
      const float4 b = *(const float4*)&Bs[kk][tx * 4];
      const float av[4] = {a.x, a.y, a.z, a.w};
      const float bv[4] = {b.x, b.y, b.z, b.w};
      #pragma unroll
      for (int i = 0; i < 4; ++i)
        #pragma unroll
        for (int j = 0; j < 4; ++j)
          acc[i][j] = fmaf(av[i], bv[j], acc[i][j]);
    }
    __syncthreads();
  }

  #pragma unroll
  for (int i = 0; i < 4; ++i) {
    int r = bm + ty * 4 + i;
    if (r >= M) continue;
    #pragma unroll
    for (int j = 0; j < 4; ++j) {
      int c = bn + tx * 4 + j;
      if (c >= N) continue;
      float val = acc[i][j];
      if (bias) val += bias[c];
      if (act == 1) val = fmaxf(val, 0.f);
      else if (act == 2) val = val > 0.f ? val : 0.01f * val;
      C[(size_t)r * N + c] = val;
    }
  }
}

// ---------------------------------------------------------------------------
// LayerNorm over rows of 128. One wave per row, 4 rows per 256-block.
// If X2 != null, normalizes (X + X2).
// ---------------------------------------------------------------------------
__global__ __launch_bounds__(256) void ln_kernel(
    const float* __restrict__ X, const float* __restrict__ X2,
    const float* __restrict__ g, const float* __restrict__ b,
    float* __restrict__ Y, int n)
{
  int row = blockIdx.x * 4 + (threadIdx.x >> 6);
  int lane = threadIdx.x & 63;
  if (row >= n) return;
  float2 x = *(const float2*)(X + (size_t)row * DH + lane * 2);
  if (X2) {
    float2 y = *(const float2*)(X2 + (size_t)row * DH + lane * 2);
    x.x += y.x; x.y += y.y;
  }
  float s = x.x + x.y;
  #pragma unroll
  for (int m = 32; m >= 1; m >>= 1) s += __shfl_xor(s, m);
  float mean = s * (1.f / 128.f);
  float dx = x.x - mean, dy = x.y - mean;
  float v = dx * dx + dy * dy;
  #pragma unroll
  for (int m = 32; m >= 1; m >>= 1) v += __shfl_xor(v, m);
  float rstd = rsqrtf(v * (1.f / 128.f) + 1e-5f);
  float2 gg = *(const float2*)(g + lane * 2);
  float2 bb = *(const float2*)(b + lane * 2);
  float2 o;
  o.x = dx * rstd * gg.x + bb.x;
  o.y = dy * rstd * gg.y + bb.y;
  *(float2*)(Y + (size_t)row * DH + lane * 2) = o;
}

// ---------------------------------------------------------------------------
// Edge kernels: global softmax over E edge logits.
// ---------------------------------------------------------------------------
__device__ inline void atomicMaxF(float* addr, float val) {
  if (val >= 0.f) atomicMax((int*)addr, __float_as_int(val));
  else            atomicMin((unsigned int*)addr, __float_as_uint(val));
}

__global__ void init_scalars(float* scal) {
  if (threadIdx.x == 0) { scal[0] = -INFINITY; scal[1] = 0.f; }
}

// s_e[e] = dot(q[dst], k[src]); track global max. 32 lanes per edge.
__global__ __launch_bounds__(256) void attn_logits(
    const int* __restrict__ ei, const float* __restrict__ q,
    const float* __restrict__ k, float* __restrict__ s_e,
    float* __restrict__ scal, int E)
{
  const int tid = threadIdx.x;
  const int e = blockIdx.x * 8 + (tid >> 5);
  const int lane = tid & 31;
  float val = -FLT_MAX;
  if (e < E) {
    int src = ei[e], dst = ei[E + e];
    float4 qv = *(const float4*)(q + (size_t)dst * DH + lane * 4);
    float4 kv = *(const float4*)(k + (size_t)src * DH + lane * 4);
    float d = qv.x * kv.x + qv.y * kv.y + qv.z * kv.z + qv.w * kv.w;
    #pragma unroll
    for (int m = 16; m >= 1; m >>= 1) d += __shfl_xor(d, m);  // within 32-group
    if (lane == 0) s_e[e] = d;
    val = d;
  }
  // block max -> global atomic max
  float wm = fmaxf(val, __shfl_xor(val, 32));  // 64-lane wave max
  __shared__ float red[4];
  if ((tid & 63) == 0) red[tid >> 6] = wm;
  __syncthreads();
  if (tid == 0)
    atomicMaxF(scal, fmaxf(fmaxf(red[0], red[1]), fmaxf(red[2], red[3])));
}

// s_e[e] = exp(s_e[e] - max); accumulate Z.
__global__ __launch_bounds__(256) void exp_sum(
    float* __restrict__ s_e, const float* __restrict__ scal,
    float* __restrict__ Z, int E)
{
  const int e = blockIdx.x * 256 + threadIdx.x;
  const float mx = scal[0];
  float v = 0.f;
  if (e < E) {
    v = expf(s_e[e] - mx);
    s_e[e] = v;
  }
  #pragma unroll
  for (int m = 32; m >= 1; m >>= 1) v += __shfl_xor(v, m);
  __shared__ float red[4];
  if ((threadIdx.x & 63) == 0) red[threadIdx.x >> 6] = v;
  __syncthreads();
  if (threadIdx.x == 0) atomicAdd(Z, red[0] + red[1] + red[2] + red[3]);
}

// msg = (s_e/Z) * v[src] * sigmoid(edge_attr + hi[src] + hj[dst]); h[dst] += msg
__global__ __launch_bounds__(256) void edge_msg(
    const int* __restrict__ ei, const float* __restrict__ s_e,
    const float* __restrict__ Z, const float* __restrict__ v,
    const float* __restrict__ hi, const float* __restrict__ hj,
    const float* __restrict__ ea, float* __restrict__ h, int E)
{
  const int tid = threadIdx.x;
  const int e = blockIdx.x * 8 + (tid >> 5);
  if (e >= E) return;
  const int lane = tid & 31;
  const float invZ = 1.f / Z[0];
  const int src = ei[e], dst = ei[E + e];
  const float p = s_e[e] * invZ;
  const size_t off = (size_t)lane * 4;
  float4 eav = *(const float4*)(ea + (size_t)e * DH + off);
  float4 hiv = *(const float4*)(hi + (size_t)src * DH + off);
  float4 hjv = *(const float4*)(hj + (size_t)dst * DH + off);
  float4 vv  = *(const float4*)(v  + (size_t)src * DH + off);
  float gx = 1.f / (1.f + expf(-(eav.x + hiv.x + hjv.x)));
  float gy = 1.f / (1.f + expf(-(eav.y + hiv.y + hjv.y)));
  float gz = 1.f / (1.f + expf(-(eav.z + hiv.z + hjv.z)));
  float gw = 1.f / (1.f + expf(-(eav.w + hiv.w + hjv.w)));
  float* hp = h + (size_t)dst * DH + off;
  atomicAdd(hp + 0, p * vv.x * gx);
  atomicAdd(hp + 1, p * vv.y * gy);
  atomicAdd(hp + 2, p * vv.z * gz);
  atomicAdd(hp + 3, p * vv.w * gw);
}

// ---------------------------------------------------------------------------
extern "C" void kernel_launch(void* const* d_in, const int* in_sizes, int n_in,
                              void* d_out, int out_size, void* d_ws, size_t ws_size,
                              hipStream_t stream)
{
  const float* x_in  = (const float*)d_in[0];
  const int*   ei    = (const int*)d_in[1];
  const float* ea    = (const float*)d_in[2];
  const float* Wq    = (const float*)d_in[3];
  const float* bq    = (const float*)d_in[4];
  const float* Wk    = (const float*)d_in[5];
  const float* bk    = (const float*)d_in[6];
  const float* Wv    = (const float*)d_in[7];
  const float* bv    = (const float*)d_in[8];
  const float* Wr    = (const float*)d_in[9];
  const float* br    = (const float*)d_in[10];
  const float* Whi   = (const float*)d_in[11];
  const float* Whj   = (const float*)d_in[12];
  const float* W1    = (const float*)d_in[13];
  const float* b1    = (const float*)d_in[14];
  const float* W2    = (const float*)d_in[15];
  const float* b2    = (const float*)d_in[16];
  const float* g1    = (const float*)d_in[17];
  const float* be1   = (const float*)d_in[18];
  const float* g2    = (const float*)d_in[19];
  const float* be2   = (const float*)d_in[20];
  const float* linW  = (const float*)d_in[21];
  const float* linb  = (const float*)d_in[22];
  const float* lin2W = (const float*)d_in[23];
  const float* lin2b = (const float*)d_in[24];
  float* out = (float*)d_out;

  // workspace layout (floats): ~249 MB total
  float* ws    = (float*)d_ws;
  float* x_buf = ws;                              // NN*DIN
  float* q     = x_buf + (size_t)NN * DIN;        // NN*DH each below
  float* k     = q   + (size_t)NN * DH;
  float* v     = k   + (size_t)NN * DH;
  float* hi    = v   + (size_t)NN * DH;
  float* hj    = hi  + (size_t)NN * DH;
  float* h     = hj  + (size_t)NN * DH;
  float* ss    = h   + (size_t)NN * DH;
  float* ss2   = ss  + (size_t)NN * DH;
  float* ff1   = ss2 + (size_t)NN * DH;           // NN*DFF
  float* s_e   = ff1 + (size_t)NN * DFF;          // EE
  float* scal  = s_e + EE;                        // [max, Z]

  const dim3 blk(256);
  auto grid2d = [](int M, int N) {
    return dim3((M + BM - 1) / BM, (N + BN - 1) / BN);
  };

  for (int l = 0; l < NLAYER; ++l) {
    const float* xp = (l == 0) ? x_in : x_buf;
    const size_t wo = (size_t)l * DIN * DH;
    // 6 input projections (r written straight into h; aggr atomically added later)
    gemm_f32<<<grid2d(NN, DH), blk, 0, stream>>>(xp, Wq + wo, bq + l * DH, q,  NN, DH, DIN, 0);
    gemm_f32<<<grid2d(NN, DH), blk, 0, stream>>>(xp, Wk + wo, bk + l * DH, k,  NN, DH, DIN, 0);
    gemm_f32<<<grid2d(NN, DH), blk, 0, stream>>>(xp, Wv + wo, bv + l * DH, v,  NN, DH, DIN, 0);
    gemm_f32<<<grid2d(NN, DH), blk, 0, stream>>>(xp, Wr + wo, br + l * DH, h,  NN, DH, DIN, 0);
    gemm_f32<<<grid2d(NN, DH), blk, 0, stream>>>(xp, Whi + wo, nullptr,    hi, NN, DH, DIN, 0);
    gemm_f32<<<grid2d(NN, DH), blk, 0, stream>>>(xp, Whj + wo, nullptr,    hj, NN, DH, DIN, 0);
    // global softmax attention + gated message + scatter-add
    init_scalars<<<1, 64, 0, stream>>>(scal);
    attn_logits<<<EE / 8, blk, 0, stream>>>(ei, q, k, s_e, scal, EE);
    exp_sum<<<EE / 256, blk, 0, stream>>>(s_e, scal, scal + 1, EE);
    edge_msg<<<EE / 8, blk, 0, stream>>>(ei, s_e, scal + 1, v, hi, hj, ea, h, EE);
    // FFMLP with pre-norm residual
    ln_kernel<<<(NN + 3) / 4, blk, 0, stream>>>(h, nullptr, g1 + l * DH, be1 + l * DH, ss, NN);
    gemm_f32<<<grid2d(NN, DFF), blk, 0, stream>>>(ss, W1 + (size_t)l * DH * DFF, b1 + l * DFF, ff1, NN, DFF, DH, 1);
    gemm_f32<<<grid2d(NN, DH), blk, 0, stream>>>(ff1, W2 + (size_t)l * DFF * DH, b2 + l * DH, ss2, NN, DH, DFF, 0);
    ln_kernel<<<(NN + 3) / 4, blk, 0, stream>>>(ss, ss2, g2 + l * DH, be2 + l * DH, h, NN);
    // shared linear 128 -> 1546 (overwrites x_buf; safe: all readers are done)
    gemm_f32<<<grid2d(NN, DIN), blk, 0, stream>>>(h, linW, linb, x_buf, NN, DIN, DH, 0);
  }
  // final 1546 -> 128 with leaky_relu
  gemm_f32<<<grid2d(NN, DH), blk, 0, stream>>>(x_buf, lin2W, lin2b, out, NN, DH, DIN, 2);
}

// Round 2
// 3325.085 us; speedup vs baseline: 2.6598x; 2.6598x over previous
//
#include <hip/hip_runtime.h>
#include <cfloat>
#include <cmath>

#define NN 20000
#define EE 640000
#define DIN 1546
#define KIN 1568   // DIN padded to multiple of 32
#define DH 128
#define DFF 512
#define NL 2
#define NPROJ 768   // q|k|v|r|hi|hj packed columns
#define LINNP 1664  // lin Bt padded rows (13*128)
#define LINNS 1568  // lin output width (KIN)

typedef unsigned short ushort_t;
typedef __attribute__((ext_vector_type(8))) short short8;
typedef __attribute__((ext_vector_type(8))) unsigned short ushort8;
typedef __attribute__((ext_vector_type(4))) float floatx4;

__device__ inline ushort_t f2bf(float f) {
  unsigned u = __float_as_uint(f);
  unsigned r = (u + 0x7FFF + ((u >> 16) & 1)) >> 16;
  return (ushort_t)r;
}
__device__ inline float bflo(unsigned u) { return __uint_as_float(u << 16); }
__device__ inline float bfhi(unsigned u) { return __uint_as_float(u & 0xFFFF0000u); }

// ---------------------------------------------------------------------------
// bf16 MFMA GEMM: C[M x N] = act(A[M x K] @ Bt[N x K]^T + bias)
// A, Bt bf16 (ushort). K % 32 == 0, lda/ldb % 8 == 0. Grid: (ceil(M/128), N/128)
// with Bt zero-padded to gridDim.y*128 rows. Stores guarded by row<M, col<Nstore.
// LDS layout [kq][row][8] with plane stride 1032 elems (bank-uniform).
// act: 0 none, 1 relu, 2 leaky(0.01).  out_bf16: 1 -> ushort C, 0 -> float C.
// ---------------------------------------------------------------------------
__global__ __launch_bounds__(256) void gemm_bf16(
    const ushort_t* __restrict__ A, int lda,
    const ushort_t* __restrict__ Bt, int ldb,
    const float* __restrict__ bias, void* __restrict__ Cv, int ldc,
    int M, int Nstore, int K, int act, int out_bf16)
{
  __shared__ ushort_t As[4 * 1032];
  __shared__ ushort_t Bs[4 * 1032];
  const int tid = threadIdx.x;
  const int wave = tid >> 6, lane = tid & 63;
  const int bm = blockIdx.x * 128, bn = blockIdx.y * 128;
  const int wm = (wave >> 1) * 64, wn = (wave & 1) * 64;
  const int frow = lane & 15, kq = lane >> 4;

  floatx4 acc[4][4];
  #pragma unroll
  for (int i = 0; i < 4; ++i)
    #pragma unroll
    for (int j = 0; j < 4; ++j) acc[i][j] = (floatx4){0.f, 0.f, 0.f, 0.f};

  // staging: thread covers (row = tid>>2 [+64], kchunk = tid&3)
  const int srow = tid >> 2, skc = tid & 3;
  const int ar0 = min(bm + srow, M - 1);
  const int ar1 = min(bm + srow + 64, M - 1);
  const ushort_t* Ap0 = A + (size_t)ar0 * lda + skc * 8;
  const ushort_t* Ap1 = A + (size_t)ar1 * lda + skc * 8;
  const ushort_t* Bp0 = Bt + (size_t)(bn + srow) * ldb + skc * 8;
  const ushort_t* Bp1 = Bt + (size_t)(bn + srow + 64) * ldb + skc * 8;
  ushort_t* Aw0 = As + skc * 1032 + srow * 8;
  ushort_t* Aw1 = As + skc * 1032 + (srow + 64) * 8;
  ushort_t* Bw0 = Bs + skc * 1032 + srow * 8;
  ushort_t* Bw1 = Bs + skc * 1032 + (srow + 64) * 8;

  for (int k0 = 0; k0 < K; k0 += 32) {
    ushort8 a0 = *(const ushort8*)Ap0; Ap0 += 32;
    ushort8 a1 = *(const ushort8*)Ap1; Ap1 += 32;
    ushort8 b0 = *(const ushort8*)Bp0; Bp0 += 32;
    ushort8 b1 = *(const ushort8*)Bp1; Bp1 += 32;
    __syncthreads();
    *(ushort8*)Aw0 = a0; *(ushort8*)Aw1 = a1;
    *(ushort8*)Bw0 = b0; *(ushort8*)Bw1 = b1;
    __syncthreads();
    short8 af[4], bf[4];
    #pragma unroll
    for (int i = 0; i < 4; ++i)
      af[i] = *(const short8*)(As + kq * 1032 + (wm + i * 16 + frow) * 8);
    #pragma unroll
    for (int j = 0; j < 4; ++j)
      bf[j] = *(const short8*)(Bs + kq * 1032 + (wn + j * 16 + frow) * 8);
    #pragma unroll
    for (int i = 0; i < 4; ++i)
      #pragma unroll
      for (int j = 0; j < 4; ++j)
        acc[i][j] = __builtin_amdgcn_mfma_f32_16x16x32_bf16(af[i], bf[j], acc[i][j], 0, 0, 0);
  }

  const int rq = (lane >> 4) * 4;
  #pragma unroll
  for (int j = 0; j < 4; ++j) {
    int col = bn + wn + j * 16 + frow;
    if (col >= Nstore) continue;
    float bb = bias ? bias[col] : 0.f;
    #pragma unroll
    for (int i = 0; i < 4; ++i) {
      #pragma unroll
      for (int r = 0; r < 4; ++r) {
        int row = bm + wm + i * 16 + rq + r;
        if (row >= M) continue;
        float v = acc[i][j][r] + bb;
        if (act == 1) v = fmaxf(v, 0.f);
        else if (act == 2) v = v > 0.f ? v : 0.01f * v;
        if (out_bf16) ((ushort_t*)Cv)[(size_t)row * ldc + col] = f2bf(v);
        else          ((float*)Cv)[(size_t)row * ldc + col] = v;
      }
    }
  }
}

// ---------------------------------------------------------------------------
// Pack / convert kernels (run per call; weights are restored every launch)
// ---------------------------------------------------------------------------
__global__ void convert_x_kernel(const float* __restrict__ x, ushort_t* __restrict__ xb) {
  int c = blockIdx.x * 256 + threadIdx.x;
  int row = blockIdx.y;
  if (c >= KIN) return;
  xb[(size_t)row * KIN + c] = (c < DIN) ? f2bf(x[(size_t)row * DIN + c]) : (ushort_t)0;
}

__global__ void pack6_kernel(const float* __restrict__ Wq, const float* __restrict__ Wk,
                             const float* __restrict__ Wv, const float* __restrict__ Wr,
                             const float* __restrict__ Whi, const float* __restrict__ Whj,
                             ushort_t* __restrict__ Wt6) {
  int k = blockIdx.x * 256 + threadIdx.x;
  int n = blockIdx.y;
  if (k >= KIN) return;
  const float* W[6] = {Wq, Wk, Wv, Wr, Whi, Whj};
  int which = n >> 7, col = n & 127;
  float v = (k < DIN) ? W[which][(size_t)k * DH + col] : 0.f;
  Wt6[(size_t)n * KIN + k] = f2bf(v);
}

// dst[n][k] (stride Kp) = bf16(src[k*Nsrc + n]) with zero padding
__global__ void pack_bt_kernel(const float* __restrict__ src, ushort_t* __restrict__ dst,
                               int Nsrc, int Ksrc, int Kp) {
  int k = blockIdx.x * 256 + threadIdx.x;
  int n = blockIdx.y;
  if (k >= Kp) return;
  float v = (n < Nsrc && k < Ksrc) ? src[(size_t)k * Nsrc + n] : 0.f;
  dst[(size_t)n * Kp + k] = f2bf(v);
}

__global__ void pack_bias_kernel(const float* __restrict__ bq, const float* __restrict__ bk,
                                 const float* __restrict__ bv, const float* __restrict__ br,
                                 float* __restrict__ out) {
  int n = blockIdx.x * 256 + threadIdx.x;
  if (n >= NPROJ) return;
  int which = n >> 7, c = n & 127;
  float v = 0.f;
  if (which == 0) v = bq[c]; else if (which == 1) v = bk[c];
  else if (which == 2) v = bv[c]; else if (which == 3) v = br[c];
  out[n] = v;
}

__global__ void pad_linb_kernel(const float* __restrict__ linb, float* __restrict__ out) {
  int n = blockIdx.x * 256 + threadIdx.x;
  if (n >= LINNS) return;
  out[n] = (n < DIN) ? linb[n] : 0.f;
}

// ---------------------------------------------------------------------------
// CSR build (once per call; edge_index constant across layers)
// ---------------------------------------------------------------------------
__global__ void hist_kernel(const int* __restrict__ ei, int* __restrict__ counts) {
  int e = blockIdx.x * 256 + threadIdx.x;
  if (e < EE) atomicAdd(&counts[ei[EE + e]], 1);
}

__global__ __launch_bounds__(1024) void scan_kernel(const int* __restrict__ counts,
                                                    int* __restrict__ offsets,
                                                    int* __restrict__ cursor) {
  __shared__ int sums[1024];
  const int t = threadIdx.x;
  const int PER = 20;  // 1024*20 = 20480 >= NN
  int base = t * PER;
  int loc[PER]; int s = 0;
  #pragma unroll
  for (int i = 0; i < PER; ++i) {
    int idx = base + i;
    int c = (idx < NN) ? counts[idx] : 0;
    loc[i] = s; s += c;
  }
  sums[t] = s;
  __syncthreads();
  for (int d = 1; d < 1024; d <<= 1) {
    int v = (t >= d) ? sums[t - d] : 0;
    __syncthreads();
    sums[t] += v;
    __syncthreads();
  }
  int pre = (t > 0) ? sums[t - 1] : 0;
  #pragma unroll
  for (int i = 0; i < PER; ++i) {
    int idx = base + i;
    if (idx < NN) { offsets[idx] = pre + loc[i]; cursor[idx] = pre + loc[i]; }
  }
  if (t == 0) offsets[NN] = sums[1023];
}

__global__ void scatter_kernel(const int* __restrict__ ei, int* __restrict__ cursor,
                               int* __restrict__ csr) {
  int e = blockIdx.x * 256 + threadIdx.x;
  if (e < EE) {
    int p = atomicAdd(&cursor[ei[EE + e]], 1);
    csr[p] = e;
  }
}

// ---------------------------------------------------------------------------
// Attention: global softmax over all E edge logits
// ---------------------------------------------------------------------------
__device__ inline void atomicMaxF(float* addr, float val) {
  if (val >= 0.f) atomicMax((int*)addr, __float_as_int(val));
  else            atomicMin((unsigned int*)addr, __float_as_uint(val));
}

__global__ void init_scalars(float* scal) {
  if (threadIdx.x == 0) { scal[0] = -INFINITY; scal[1] = 0.f; }
}

// s_e[e] = dot(q[dst], k[src]) from packed bf16 qkv; track global max.
__global__ __launch_bounds__(256) void attn_logits(
    const int* __restrict__ ei, const ushort_t* __restrict__ qkv,
    float* __restrict__ s_e, float* __restrict__ scal)
{
  const int tid = threadIdx.x;
  const int e = blockIdx.x * 8 + (tid >> 5);
  const int l = tid & 31;
  const int src = ei[e], dst = ei[EE + e];
  uint2 qu = *(const uint2*)(qkv + (size_t)dst * NPROJ + l * 4);
  uint2 ku = *(const uint2*)(qkv + (size_t)src * NPROJ + DH + l * 4);
  float d = bflo(qu.x) * bflo(ku.x) + bfhi(qu.x) * bfhi(ku.x)
          + bflo(qu.y) * bflo(ku.y) + bfhi(qu.y) * bfhi(ku.y);
  #pragma unroll
  for (int m = 16; m >= 1; m >>= 1) d += __shfl_xor(d, m);
  if (l == 0) s_e[e] = d;
  float wm_ = fmaxf(d, __shfl_xor(d, 32));
  __shared__ float red[4];
  if ((tid & 63) == 0) red[tid >> 6] = wm_;
  __syncthreads();
  if (tid == 0)
    atomicMaxF(scal, fmaxf(fmaxf(red[0], red[1]), fmaxf(red[2], red[3])));
}

__global__ __launch_bounds__(256) void exp_sum(
    float* __restrict__ s_e, const float* __restrict__ scal, float* __restrict__ Z)
{
  const int e = blockIdx.x * 256 + threadIdx.x;
  const float mx = scal[0];
  float v = __expf(s_e[e] - mx);
  s_e[e] = v;
  float t = v;
  #pragma unroll
  for (int m = 32; m >= 1; m >>= 1) t += __shfl_xor(t, m);
  __shared__ float red[4];
  if ((threadIdx.x & 63) == 0) red[threadIdx.x >> 6] = t;
  __syncthreads();
  if (threadIdx.x == 0) atomicAdd(Z, red[0] + red[1] + red[2] + red[3]);
}

// ---------------------------------------------------------------------------
// Fused per-dst aggregation: h[i] = r[i] + sum_e p_e * v[src] * gate_e
// One wave per node; 2 channels per lane; hj[dst]/r[dst] cached in regs.
// ---------------------------------------------------------------------------
__global__ __launch_bounds__(256) void aggregate_kernel(
    const int* __restrict__ ei, const int* __restrict__ offsets,
    const int* __restrict__ csr, const float* __restrict__ s_e,
    const float* __restrict__ scal, const ushort_t* __restrict__ qkv,
    const float* __restrict__ ea, float* __restrict__ h)
{
  const int node = blockIdx.x * 4 + (threadIdx.x >> 6);
  const int lane = threadIdx.x & 63;
  if (node >= NN) return;
  const int off = offsets[node];
  const int deg = offsets[node + 1] - off;
  const float invZ = 1.f / scal[1];
  const ushort_t* bd = qkv + (size_t)node * NPROJ;
  unsigned hjp = *(const unsigned*)(bd + 640 + lane * 2);
  unsigned rp  = *(const unsigned*)(bd + 384 + lane * 2);
  const float hj0 = bflo(hjp), hj1 = bfhi(hjp);
  float a0 = bflo(rp), a1 = bfhi(rp);
  for (int b0 = 0; b0 < deg; b0 += 64) {
    int t = b0 + lane;
    int eL = (t < deg) ? csr[off + t] : 0;
    int sL = (t < deg) ? ei[eL] : 0;
    float pL = (t < deg) ? s_e[eL] * invZ : 0.f;
    int cnt = min(64, deg - b0);
    for (int u = 0; u < cnt; ++u) {
      int e = __shfl(eL, u);
      int src = __shfl(sL, u);
      float p = __shfl(pL, u);
      const ushort_t* bs = qkv + (size_t)src * NPROJ;
      unsigned vv = *(const unsigned*)(bs + 256 + lane * 2);
      unsigned hv = *(const unsigned*)(bs + 512 + lane * 2);
      float2 eav = *(const float2*)(ea + (size_t)e * DH + lane * 2);
      float g0 = 1.f / (1.f + __expf(-(eav.x + bflo(hv) + hj0)));
      float g1 = 1.f / (1.f + __expf(-(eav.y + bfhi(hv) + hj1)));
      a0 = fmaf(p * bflo(vv), g0, a0);
      a1 = fmaf(p * bfhi(vv), g1, a1);
    }
  }
  *(float2*)(h + (size_t)node * DH + lane * 2) = make_float2(a0, a1);
}

// ---------------------------------------------------------------------------
// LayerNorm over rows of 128 (optionally X+X2), writes f32 and/or bf16.
// ---------------------------------------------------------------------------
__global__ __launch_bounds__(256) void ln_kernel(
    const float* __restrict__ X, const float* __restrict__ X2,
    const float* __restrict__ g, const float* __restrict__ b,
    float* __restrict__ Yf, ushort_t* __restrict__ Yb)
{
  int row = blockIdx.x * 4 + (threadIdx.x >> 6);
  int lane = threadIdx.x & 63;
  if (row >= NN) return;
  float2 x = *(const float2*)(X + (size_t)row * DH + lane * 2);
  if (X2) {
    float2 y = *(const float2*)(X2 + (size_t)row * DH + lane * 2);
    x.x += y.x; x.y += y.y;
  }
  float s = x.x + x.y;
  #pragma unroll
  for (int m = 32; m >= 1; m >>= 1) s += __shfl_xor(s, m);
  float mean = s * (1.f / 128.f);
  float dx = x.x - mean, dy = x.y - mean;
  float v = dx * dx + dy * dy;
  #pragma unroll
  for (int m = 32; m >= 1; m >>= 1) v += __shfl_xor(v, m);
  float rstd = rsqrtf(v * (1.f / 128.f) + 1e-5f);
  float2 gg = *(const float2*)(g + lane * 2);
  float2 bb = *(const float2*)(b + lane * 2);
  float o0 = dx * rstd * gg.x + bb.x;
  float o1 = dy * rstd * gg.y + bb.y;
  if (Yf) *(float2*)(Yf + (size_t)row * DH + lane * 2) = make_float2(o0, o1);
  if (Yb) {
    ushort_t* p = Yb + (size_t)row * DH + lane * 2;
    p[0] = f2bf(o0); p[1] = f2bf(o1);
  }
}

// ---------------------------------------------------------------------------
extern "C" void kernel_launch(void* const* d_in, const int* in_sizes, int n_in,
                              void* d_out, int out_size, void* d_ws, size_t ws_size,
                              hipStream_t stream)
{
  const float* x_in  = (const float*)d_in[0];
  const int*   ei    = (const int*)d_in[1];
  const float* ea    = (const float*)d_in[2];
  const float* Wq    = (const float*)d_in[3];
  const float* bq    = (const float*)d_in[4];
  const float* Wk    = (const float*)d_in[5];
  const float* bk    = (const float*)d_in[6];
  const float* Wv    = (const float*)d_in[7];
  const float* bv    = (const float*)d_in[8];
  const float* Wr    = (const float*)d_in[9];
  const float* br    = (const float*)d_in[10];
  const float* Whi   = (const float*)d_in[11];
  const float* Whj   = (const float*)d_in[12];
  const float* W1    = (const float*)d_in[13];
  const float* b1    = (const float*)d_in[14];
  const float* W2    = (const float*)d_in[15];
  const float* b2    = (const float*)d_in[16];
  const float* g1    = (const float*)d_in[17];
  const float* be1   = (const float*)d_in[18];
  const float* g2    = (const float*)d_in[19];
  const float* be2   = (const float*)d_in[20];
  const float* linW  = (const float*)d_in[21];
  const float* linb  = (const float*)d_in[22];
  const float* lin2W = (const float*)d_in[23];
  const float* lin2b = (const float*)d_in[24];
  float* out = (float*)d_out;

  // bump allocator over d_ws (64B aligned)
  char* p = (char*)d_ws;
  auto alloc = [&](size_t bytes) -> void* {
    void* r = (void*)p; p += (bytes + 63) & ~((size_t)63); return r;
  };
  ushort_t* x_bf   = (ushort_t*)alloc((size_t)NN * KIN * 2);
  ushort_t* qkvp   = (ushort_t*)alloc((size_t)NN * NPROJ * 2);
  ushort_t* Wt6    = (ushort_t*)alloc((size_t)NPROJ * KIN * 2);
  ushort_t* W1t    = (ushort_t*)alloc((size_t)DFF * DH * 2);
  ushort_t* W2t    = (ushort_t*)alloc((size_t)DH * DFF * 2);
  ushort_t* lint   = (ushort_t*)alloc((size_t)LINNP * DH * 2);
  ushort_t* lin2t  = (ushort_t*)alloc((size_t)DH * KIN * 2);
  float*    bias768= (float*)alloc(NPROJ * 4);
  float*    linbp  = (float*)alloc(LINNS * 4);
  float*    s_e    = (float*)alloc((size_t)EE * 4);
  float*    scal   = (float*)alloc(64);
  int*      counts = (int*)alloc((size_t)NN * 4);
  int*      offsets= (int*)alloc((size_t)(NN + 1) * 4);
  int*      cursor = (int*)alloc((size_t)NN * 4);
  int*      csr    = (int*)alloc((size_t)EE * 4);
  float*    h      = (float*)alloc((size_t)NN * DH * 4);
  float*    ss     = (float*)alloc((size_t)NN * DH * 4);
  ushort_t* ssbf   = (ushort_t*)alloc((size_t)NN * DH * 2);
  ushort_t* ff1bf  = (ushort_t*)alloc((size_t)NN * DFF * 2);
  float*    ss2    = (float*)alloc((size_t)NN * DH * 4);
  ushort_t* h2bf   = (ushort_t*)alloc((size_t)NN * DH * 2);

  const dim3 blk(256);
  const int MB = (NN + 127) / 128;  // 157

  // --- setup: convert x, pack shared weights, build CSR (once) ---
  convert_x_kernel<<<dim3(7, NN), blk, 0, stream>>>(x_in, x_bf);
  pack_bt_kernel<<<dim3(1, LINNP), blk, 0, stream>>>(linW, lint, DIN, DH, DH);
  pack_bt_kernel<<<dim3(7, DH), blk, 0, stream>>>(lin2W, lin2t, DH, DIN, KIN);
  pad_linb_kernel<<<dim3(7), blk, 0, stream>>>(linb, linbp);
  hipMemsetAsync(counts, 0, (size_t)NN * 4, stream);
  hist_kernel<<<dim3(EE / 256), blk, 0, stream>>>(ei, counts);
  scan_kernel<<<dim3(1), dim3(1024), 0, stream>>>(counts, offsets, cursor);
  scatter_kernel<<<dim3(EE / 256), blk, 0, stream>>>(ei, cursor, csr);

  for (int l = 0; l < NL; ++l) {
    const size_t wo = (size_t)l * DIN * DH;
    pack6_kernel<<<dim3(7, NPROJ), blk, 0, stream>>>(
        Wq + wo, Wk + wo, Wv + wo, Wr + wo, Whi + wo, Whj + wo, Wt6);
    pack_bias_kernel<<<dim3(3), blk, 0, stream>>>(
        bq + (size_t)l * DH, bk + (size_t)l * DH, bv + (size_t)l * DH, br + (size_t)l * DH, bias768);
    pack_bt_kernel<<<dim3(1, DFF), blk, 0, stream>>>(W1 + (size_t)l * DH * DFF, W1t, DFF, DH, DH);
    pack_bt_kernel<<<dim3(2, DH), blk, 0, stream>>>(W2 + (size_t)l * DFF * DH, W2t, DH, DFF, DFF);

    // fused 6-way projection: qkvp[N][768] bf16
    gemm_bf16<<<dim3(MB, 6), blk, 0, stream>>>(
        x_bf, KIN, Wt6, KIN, bias768, qkvp, NPROJ, NN, NPROJ, KIN, 0, 1);

    // global-softmax attention + aggregation
    init_scalars<<<1, 64, 0, stream>>>(scal);
    attn_logits<<<dim3(EE / 8), blk, 0, stream>>>(ei, qkvp, s_e, scal);
    exp_sum<<<dim3(EE / 256), blk, 0, stream>>>(s_e, scal, scal + 1);
    aggregate_kernel<<<dim3(NN / 4), blk, 0, stream>>>(
        ei, offsets, csr, s_e, scal, qkvp, ea, h);

    // FFMLP with pre-norm residual
    ln_kernel<<<dim3(NN / 4), blk, 0, stream>>>(h, nullptr, g1 + (size_t)l * DH, be1 + (size_t)l * DH, ss, ssbf);
    gemm_bf16<<<dim3(MB, 4), blk, 0, stream>>>(
        ssbf, DH, W1t, DH, b1 + (size_t)l * DFF, ff1bf, DFF, NN, DFF, DH, 1, 1);
    gemm_bf16<<<dim3(MB, 1), blk, 0, stream>>>(
        ff1bf, DFF, W2t, DFF, b2 + (size_t)l * DH, ss2, DH, NN, DH, DFF, 0, 0);
    ln_kernel<<<dim3(NN / 4), blk, 0, stream>>>(ss, ss2, g2 + (size_t)l * DH, be2 + (size_t)l * DH, nullptr, h2bf);

    // shared linear 128 -> 1546 (writes padded bf16 x for next layer / final)
    gemm_bf16<<<dim3(MB, 13), blk, 0, stream>>>(
        h2bf, DH, lint, DH, linbp, x_bf, KIN, NN, LINNS, DH, 0, 1);
  }

  // final 1546 -> 128 + leaky_relu, fp32 out
  gemm_bf16<<<dim3(MB, 1), blk, 0, stream>>>(
      x_bf, KIN, lin2t, KIN, lin2b, out, DH, NN, DH, KIN, 2, 0);
}

// Round 3
// 1614.298 us; speedup vs baseline: 5.4786x; 2.0598x over previous
//
#include <hip/hip_runtime.h>
#include <cfloat>
#include <cmath>

#define NN 20000
#define EE 640000
#define DIN 1546
#define KIN 1568   // DIN padded to multiple of 32
#define DH 128
#define DFF 512
#define NL 2
#define NPROJ 768   // q|k|v|r|hi|hj packed columns
#define LINNP 1664  // lin Bt padded rows (13*128)
#define LINNS 1568  // lin output width (KIN)
#define ALB 2048    // attn_logits blocks (one final atomic each)

typedef unsigned short ushort_t;
typedef __attribute__((ext_vector_type(8))) short short8;
typedef __attribute__((ext_vector_type(8))) unsigned short ushort8;
typedef __attribute__((ext_vector_type(4))) float floatx4;

__device__ inline ushort_t f2bf(float f) {
  unsigned u = __float_as_uint(f);
  unsigned r = (u + 0x7FFF + ((u >> 16) & 1)) >> 16;
  return (ushort_t)r;
}
__device__ inline float bflo(unsigned u) { return __uint_as_float(u << 16); }
__device__ inline float bfhi(unsigned u) { return __uint_as_float(u & 0xFFFF0000u); }

// ---------------------------------------------------------------------------
// bf16 MFMA GEMM: C[M x N] = act(A[M x K] @ Bt[N x K]^T + bias)
// A, Bt bf16 (ushort). K % 32 == 0, lda/ldb % 8 == 0. Grid: (ceil(M/128), N/128)
// with Bt zero-padded to gridDim.y*128 rows. Stores guarded by row<M, col<Nstore.
// LDS layout [kq][row][8] with plane stride 1032 elems (bank-uniform).
// act: 0 none, 1 relu, 2 leaky(0.01).  out_bf16: 1 -> ushort C, 0 -> float C.
// ---------------------------------------------------------------------------
__global__ __launch_bounds__(256) void gemm_bf16(
    const ushort_t* __restrict__ A, int lda,
    const ushort_t* __restrict__ Bt, int ldb,
    const float* __restrict__ bias, void* __restrict__ Cv, int ldc,
    int M, int Nstore, int K, int act, int out_bf16)
{
  __shared__ ushort_t As[4 * 1032];
  __shared__ ushort_t Bs[4 * 1032];
  const int tid = threadIdx.x;
  const int wave = tid >> 6, lane = tid & 63;
  const int bm = blockIdx.x * 128, bn = blockIdx.y * 128;
  const int wm = (wave >> 1) * 64, wn = (wave & 1) * 64;
  const int frow = lane & 15, kq = lane >> 4;

  floatx4 acc[4][4];
  #pragma unroll
  for (int i = 0; i < 4; ++i)
    #pragma unroll
    for (int j = 0; j < 4; ++j) acc[i][j] = (floatx4){0.f, 0.f, 0.f, 0.f};

  // staging: thread covers (row = tid>>2 [+64], kchunk = tid&3)
  const int srow = tid >> 2, skc = tid & 3;
  const int ar0 = min(bm + srow, M - 1);
  const int ar1 = min(bm + srow + 64, M - 1);
  const ushort_t* Ap0 = A + (size_t)ar0 * lda + skc * 8;
  const ushort_t* Ap1 = A + (size_t)ar1 * lda + skc * 8;
  const ushort_t* Bp0 = Bt + (size_t)(bn + srow) * ldb + skc * 8;
  const ushort_t* Bp1 = Bt + (size_t)(bn + srow + 64) * ldb + skc * 8;
  ushort_t* Aw0 = As + skc * 1032 + srow * 8;
  ushort_t* Aw1 = As + skc * 1032 + (srow + 64) * 8;
  ushort_t* Bw0 = Bs + skc * 1032 + srow * 8;
  ushort_t* Bw1 = Bs + skc * 1032 + (srow + 64) * 8;

  for (int k0 = 0; k0 < K; k0 += 32) {
    ushort8 a0 = *(const ushort8*)Ap0; Ap0 += 32;
    ushort8 a1 = *(const ushort8*)Ap1; Ap1 += 32;
    ushort8 b0 = *(const ushort8*)Bp0; Bp0 += 32;
    ushort8 b1 = *(const ushort8*)Bp1; Bp1 += 32;
    __syncthreads();
    *(ushort8*)Aw0 = a0; *(ushort8*)Aw1 = a1;
    *(ushort8*)Bw0 = b0; *(ushort8*)Bw1 = b1;
    __syncthreads();
    short8 af[4], bf[4];
    #pragma unroll
    for (int i = 0; i < 4; ++i)
      af[i] = *(const short8*)(As + kq * 1032 + (wm + i * 16 + frow) * 8);
    #pragma unroll
    for (int j = 0; j < 4; ++j)
      bf[j] = *(const short8*)(Bs + kq * 1032 + (wn + j * 16 + frow) * 8);
    #pragma unroll
    for (int i = 0; i < 4; ++i)
      #pragma unroll
      for (int j = 0; j < 4; ++j)
        acc[i][j] = __builtin_amdgcn_mfma_f32_16x16x32_bf16(af[i], bf[j], acc[i][j], 0, 0, 0);
  }

  const int rq = (lane >> 4) * 4;
  #pragma unroll
  for (int j = 0; j < 4; ++j) {
    int col = bn + wn + j * 16 + frow;
    if (col >= Nstore) continue;
    float bb = bias ? bias[col] : 0.f;
    #pragma unroll
    for (int i = 0; i < 4; ++i) {
      #pragma unroll
      for (int r = 0; r < 4; ++r) {
        int row = bm + wm + i * 16 + rq + r;
        if (row >= M) continue;
        float v = acc[i][j][r] + bb;
        if (act == 1) v = fmaxf(v, 0.f);
        else if (act == 2) v = v > 0.f ? v : 0.01f * v;
        if (out_bf16) ((ushort_t*)Cv)[(size_t)row * ldc + col] = f2bf(v);
        else          ((float*)Cv)[(size_t)row * ldc + col] = v;
      }
    }
  }
}

// ---------------------------------------------------------------------------
// Pack / convert kernels (run per call; weights are restored every launch)
// ---------------------------------------------------------------------------
__global__ void convert_x_kernel(const float* __restrict__ x, ushort_t* __restrict__ xb) {
  int c = blockIdx.x * 256 + threadIdx.x;
  int row = blockIdx.y;
  if (c >= KIN) return;
  xb[(size_t)row * KIN + c] = (c < DIN) ? f2bf(x[(size_t)row * DIN + c]) : (ushort_t)0;
}

__global__ void pack6_kernel(const float* __restrict__ Wq, const float* __restrict__ Wk,
                             const float* __restrict__ Wv, const float* __restrict__ Wr,
                             const float* __restrict__ Whi, const float* __restrict__ Whj,
                             ushort_t* __restrict__ Wt6) {
  int k = blockIdx.x * 256 + threadIdx.x;
  int n = blockIdx.y;
  if (k >= KIN) return;
  const float* W[6] = {Wq, Wk, Wv, Wr, Whi, Whj};
  int which = n >> 7, col = n & 127;
  float v = (k < DIN) ? W[which][(size_t)k * DH + col] : 0.f;
  Wt6[(size_t)n * KIN + k] = f2bf(v);
}

// dst[n][k] (stride Kp) = bf16(src[k*Nsrc + n]) with zero padding
__global__ void pack_bt_kernel(const float* __restrict__ src, ushort_t* __restrict__ dst,
                               int Nsrc, int Ksrc, int Kp) {
  int k = blockIdx.x * 256 + threadIdx.x;
  int n = blockIdx.y;
  if (k >= Kp) return;
  float v = (n < Nsrc && k < Ksrc) ? src[(size_t)k * Nsrc + n] : 0.f;
  dst[(size_t)n * Kp + k] = f2bf(v);
}

__global__ void pack_bias_kernel(const float* __restrict__ bq, const float* __restrict__ bk,
                                 const float* __restrict__ bv, const float* __restrict__ br,
                                 float* __restrict__ out) {
  int n = blockIdx.x * 256 + threadIdx.x;
  if (n >= NPROJ) return;
  int which = n >> 7, c = n & 127;
  float v = 0.f;
  if (which == 0) v = bq[c]; else if (which == 1) v = bk[c];
  else if (which == 2) v = bv[c]; else if (which == 3) v = br[c];
  out[n] = v;
}

__global__ void pad_linb_kernel(const float* __restrict__ linb, float* __restrict__ out) {
  int n = blockIdx.x * 256 + threadIdx.x;
  if (n >= LINNS) return;
  out[n] = (n < DIN) ? linb[n] : 0.f;
}

// ---------------------------------------------------------------------------
// CSR build (once per call; edge_index constant across layers)
// ---------------------------------------------------------------------------
__global__ void hist_kernel(const int* __restrict__ ei, int* __restrict__ counts) {
  int e = blockIdx.x * 256 + threadIdx.x;
  if (e < EE) atomicAdd(&counts[ei[EE + e]], 1);
}

__global__ __launch_bounds__(1024) void scan_kernel(const int* __restrict__ counts,
                                                    int* __restrict__ offsets,
                                                    int* __restrict__ cursor) {
  __shared__ int sums[1024];
  const int t = threadIdx.x;
  const int PER = 20;  // 1024*20 = 20480 >= NN
  int base = t * PER;
  int loc[PER]; int s = 0;
  #pragma unroll
  for (int i = 0; i < PER; ++i) {
    int idx = base + i;
    int c = (idx < NN) ? counts[idx] : 0;
    loc[i] = s; s += c;
  }
  sums[t] = s;
  __syncthreads();
  for (int d = 1; d < 1024; d <<= 1) {
    int v = (t >= d) ? sums[t - d] : 0;
    __syncthreads();
    sums[t] += v;
    __syncthreads();
  }
  int pre = (t > 0) ? sums[t - 1] : 0;
  #pragma unroll
  for (int i = 0; i < PER; ++i) {
    int idx = base + i;
    if (idx < NN) { offsets[idx] = pre + loc[i]; cursor[idx] = pre + loc[i]; }
  }
  if (t == 0) offsets[NN] = sums[1023];
}

__global__ void scatter_kernel(const int* __restrict__ ei, int* __restrict__ cursor,
                               int* __restrict__ csr) {
  int e = blockIdx.x * 256 + threadIdx.x;
  if (e < EE) {
    int p = atomicAdd(&cursor[ei[EE + e]], 1);
    csr[p] = e;
  }
}

// ---------------------------------------------------------------------------
// Attention: global softmax over all E edge logits
// ---------------------------------------------------------------------------
__device__ inline void atomicMaxF(float* addr, float val) {
  if (val >= 0.f) atomicMax((int*)addr, __float_as_int(val));
  else            atomicMin((unsigned int*)addr, __float_as_uint(val));
}

__global__ void init_scalars(float* scal) {
  if (threadIdx.x == 0) { scal[0] = -INFINITY; scal[1] = 0.f; }
}

// s_e[e] = dot(q[dst], k[src]) from packed bf16 qkv. Grid-stride, 2-way
// unrolled; ONE atomicMaxF per block (was: one per 8 edges -> 80k serialized).
__global__ __launch_bounds__(256) void attn_logits(
    const int* __restrict__ ei, const ushort_t* __restrict__ qkv,
    float* __restrict__ s_e, float* __restrict__ scal)
{
  const int tid = threadIdx.x;
  const int l = tid & 31;
  const int ngroups = ALB * 8;
  const int g = blockIdx.x * 8 + (tid >> 5);
  float mx = -FLT_MAX;
  for (int e = g; e < EE; e += 2 * ngroups) {
    const int e2 = e + ngroups;
    const bool has2 = (e2 < EE);
    // issue both edges' index loads, then both gathers (MLP)
    int src1 = ei[e], dst1 = ei[EE + e];
    int src2 = has2 ? ei[e2] : src1;
    int dst2 = has2 ? ei[EE + e2] : dst1;
    uint2 qu1 = *(const uint2*)(qkv + (size_t)dst1 * NPROJ + l * 4);
    uint2 ku1 = *(const uint2*)(qkv + (size_t)src1 * NPROJ + DH + l * 4);
    uint2 qu2 = *(const uint2*)(qkv + (size_t)dst2 * NPROJ + l * 4);
    uint2 ku2 = *(const uint2*)(qkv + (size_t)src2 * NPROJ + DH + l * 4);
    float d1 = bflo(qu1.x) * bflo(ku1.x) + bfhi(qu1.x) * bfhi(ku1.x)
             + bflo(qu1.y) * bflo(ku1.y) + bfhi(qu1.y) * bfhi(ku1.y);
    float d2 = bflo(qu2.x) * bflo(ku2.x) + bfhi(qu2.x) * bfhi(ku2.x)
             + bflo(qu2.y) * bflo(ku2.y) + bfhi(qu2.y) * bfhi(ku2.y);
    #pragma unroll
    for (int m = 16; m >= 1; m >>= 1) {
      d1 += __shfl_xor(d1, m);
      d2 += __shfl_xor(d2, m);
    }
    if (l == 0) {
      s_e[e] = d1;
      if (has2) s_e[e2] = d2;
    }
    mx = fmaxf(mx, has2 ? fmaxf(d1, d2) : d1);
  }
  mx = fmaxf(mx, __shfl_xor(mx, 32));
  __shared__ float red[4];
  if ((tid & 63) == 0) red[tid >> 6] = mx;
  __syncthreads();
  if (tid == 0)
    atomicMaxF(scal, fmaxf(fmaxf(red[0], red[1]), fmaxf(red[2], red[3])));
}

__global__ __launch_bounds__(256) void exp_sum(
    float* __restrict__ s_e, const float* __restrict__ scal, float* __restrict__ Z)
{
  const int e = blockIdx.x * 256 + threadIdx.x;
  const float mx = scal[0];
  float v = __expf(s_e[e] - mx);
  s_e[e] = v;
  float t = v;
  #pragma unroll
  for (int m = 32; m >= 1; m >>= 1) t += __shfl_xor(t, m);
  __shared__ float red[4];
  if ((threadIdx.x & 63) == 0) red[threadIdx.x >> 6] = t;
  __syncthreads();
  if (threadIdx.x == 0) atomicAdd(Z, red[0] + red[1] + red[2] + red[3]);
}

// ---------------------------------------------------------------------------
// Fused per-dst aggregation: h[i] = r[i] + sum_e p_e * v[src] * gate_e
// One wave per node; 2 channels per lane; hj[dst]/r[dst] cached in regs.
// ---------------------------------------------------------------------------
__global__ __launch_bounds__(256) void aggregate_kernel(
    const int* __restrict__ ei, const int* __restrict__ offsets,
    const int* __restrict__ csr, const float* __restrict__ s_e,
    const float* __restrict__ scal, const ushort_t* __restrict__ qkv,
    const float* __restrict__ ea, float* __restrict__ h)
{
  const int node = blockIdx.x * 4 + (threadIdx.x >> 6);
  const int lane = threadIdx.x & 63;
  if (node >= NN) return;
  const int off = offsets[node];
  const int deg = offsets[node + 1] - off;
  const float invZ = 1.f / scal[1];
  const ushort_t* bd = qkv + (size_t)node * NPROJ;
  unsigned hjp = *(const unsigned*)(bd + 640 + lane * 2);
  unsigned rp  = *(const unsigned*)(bd + 384 + lane * 2);
  const float hj0 = bflo(hjp), hj1 = bfhi(hjp);
  float a0 = bflo(rp), a1 = bfhi(rp);
  for (int b0 = 0; b0 < deg; b0 += 64) {
    int t = b0 + lane;
    int eL = (t < deg) ? csr[off + t] : 0;
    int sL = (t < deg) ? ei[eL] : 0;
    float pL = (t < deg) ? s_e[eL] * invZ : 0.f;
    int cnt = min(64, deg - b0);
    for (int u = 0; u < cnt; ++u) {
      int e = __shfl(eL, u);
      int src = __shfl(sL, u);
      float p = __shfl(pL, u);
      const ushort_t* bs = qkv + (size_t)src * NPROJ;
      unsigned vv = *(const unsigned*)(bs + 256 + lane * 2);
      unsigned hv = *(const unsigned*)(bs + 512 + lane * 2);
      float2 eav = *(const float2*)(ea + (size_t)e * DH + lane * 2);
      float g0 = 1.f / (1.f + __expf(-(eav.x + bflo(hv) + hj0)));
      float g1 = 1.f / (1.f + __expf(-(eav.y + bfhi(hv) + hj1)));
      a0 = fmaf(p * bflo(vv), g0, a0);
      a1 = fmaf(p * bfhi(vv), g1, a1);
    }
  }
  *(float2*)(h + (size_t)node * DH + lane * 2) = make_float2(a0, a1);
}

// ---------------------------------------------------------------------------
// LayerNorm over rows of 128 (optionally X+X2), writes f32 and/or bf16.
// ---------------------------------------------------------------------------
__global__ __launch_bounds__(256) void ln_kernel(
    const float* __restrict__ X, const float* __restrict__ X2,
    const float* __restrict__ g, const float* __restrict__ b,
    float* __restrict__ Yf, ushort_t* __restrict__ Yb)
{
  int row = blockIdx.x * 4 + (threadIdx.x >> 6);
  int lane = threadIdx.x & 63;
  if (row >= NN) return;
  float2 x = *(const float2*)(X + (size_t)row * DH + lane * 2);
  if (X2) {
    float2 y = *(const float2*)(X2 + (size_t)row * DH + lane * 2);
    x.x += y.x; x.y += y.y;
  }
  float s = x.x + x.y;
  #pragma unroll
  for (int m = 32; m >= 1; m >>= 1) s += __shfl_xor(s, m);
  float mean = s * (1.f / 128.f);
  float dx = x.x - mean, dy = x.y - mean;
  float v = dx * dx + dy * dy;
  #pragma unroll
  for (int m = 32; m >= 1; m >>= 1) v += __shfl_xor(v, m);
  float rstd = rsqrtf(v * (1.f / 128.f) + 1e-5f);
  float2 gg = *(const float2*)(g + lane * 2);
  float2 bb = *(const float2*)(b + lane * 2);
  float o0 = dx * rstd * gg.x + bb.x;
  float o1 = dy * rstd * gg.y + bb.y;
  if (Yf) *(float2*)(Yf + (size_t)row * DH + lane * 2) = make_float2(o0, o1);
  if (Yb) {
    ushort_t* p = Yb + (size_t)row * DH + lane * 2;
    p[0] = f2bf(o0); p[1] = f2bf(o1);
  }
}

// ---------------------------------------------------------------------------
extern "C" void kernel_launch(void* const* d_in, const int* in_sizes, int n_in,
                              void* d_out, int out_size, void* d_ws, size_t ws_size,
                              hipStream_t stream)
{
  const float* x_in  = (const float*)d_in[0];
  const int*   ei    = (const int*)d_in[1];
  const float* ea    = (const float*)d_in[2];
  const float* Wq    = (const float*)d_in[3];
  const float* bq    = (const float*)d_in[4];
  const float* Wk    = (const float*)d_in[5];
  const float* bk    = (const float*)d_in[6];
  const float* Wv    = (const float*)d_in[7];
  const float* bv    = (const float*)d_in[8];
  const float* Wr    = (const float*)d_in[9];
  const float* br    = (const float*)d_in[10];
  const float* Whi   = (const float*)d_in[11];
  const float* Whj   = (const float*)d_in[12];
  const float* W1    = (const float*)d_in[13];
  const float* b1    = (const float*)d_in[14];
  const float* W2    = (const float*)d_in[15];
  const float* b2    = (const float*)d_in[16];
  const float* g1    = (const float*)d_in[17];
  const float* be1   = (const float*)d_in[18];
  const float* g2    = (const float*)d_in[19];
  const float* be2   = (const float*)d_in[20];
  const float* linW  = (const float*)d_in[21];
  const float* linb  = (const float*)d_in[22];
  const float* lin2W = (const float*)d_in[23];
  const float* lin2b = (const float*)d_in[24];
  float* out = (float*)d_out;

  // bump allocator over d_ws (64B aligned)
  char* p = (char*)d_ws;
  auto alloc = [&](size_t bytes) -> void* {
    void* r = (void*)p; p += (bytes + 63) & ~((size_t)63); return r;
  };
  ushort_t* x_bf   = (ushort_t*)alloc((size_t)NN * KIN * 2);
  ushort_t* qkvp   = (ushort_t*)alloc((size_t)NN * NPROJ * 2);
  ushort_t* Wt6    = (ushort_t*)alloc((size_t)NPROJ * KIN * 2);
  ushort_t* W1t    = (ushort_t*)alloc((size_t)DFF * DH * 2);
  ushort_t* W2t    = (ushort_t*)alloc((size_t)DH * DFF * 2);
  ushort_t* lint   = (ushort_t*)alloc((size_t)LINNP * DH * 2);
  ushort_t* lin2t  = (ushort_t*)alloc((size_t)DH * KIN * 2);
  float*    bias768= (float*)alloc(NPROJ * 4);
  float*    linbp  = (float*)alloc(LINNS * 4);
  float*    s_e    = (float*)alloc((size_t)EE * 4);
  float*    scal   = (float*)alloc(64);
  int*      counts = (int*)alloc((size_t)NN * 4);
  int*      offsets= (int*)alloc((size_t)(NN + 1) * 4);
  int*      cursor = (int*)alloc((size_t)NN * 4);
  int*      csr    = (int*)alloc((size_t)EE * 4);
  float*    h      = (float*)alloc((size_t)NN * DH * 4);
  float*    ss     = (float*)alloc((size_t)NN * DH * 4);
  ushort_t* ssbf   = (ushort_t*)alloc((size_t)NN * DH * 2);
  ushort_t* ff1bf  = (ushort_t*)alloc((size_t)NN * DFF * 2);
  float*    ss2    = (float*)alloc((size_t)NN * DH * 4);
  ushort_t* h2bf   = (ushort_t*)alloc((size_t)NN * DH * 2);

  const dim3 blk(256);
  const int MB = (NN + 127) / 128;  // 157

  // --- setup: convert x, pack shared weights, build CSR (once) ---
  convert_x_kernel<<<dim3(7, NN), blk, 0, stream>>>(x_in, x_bf);
  pack_bt_kernel<<<dim3(1, LINNP), blk, 0, stream>>>(linW, lint, DIN, DH, DH);
  pack_bt_kernel<<<dim3(7, DH), blk, 0, stream>>>(lin2W, lin2t, DH, DIN, KIN);
  pad_linb_kernel<<<dim3(7), blk, 0, stream>>>(linb, linbp);
  hipMemsetAsync(counts, 0, (size_t)NN * 4, stream);
  hist_kernel<<<dim3(EE / 256), blk, 0, stream>>>(ei, counts);
  scan_kernel<<<dim3(1), dim3(1024), 0, stream>>>(counts, offsets, cursor);
  scatter_kernel<<<dim3(EE / 256), blk, 0, stream>>>(ei, cursor, csr);

  for (int l = 0; l < NL; ++l) {
    const size_t wo = (size_t)l * DIN * DH;
    pack6_kernel<<<dim3(7, NPROJ), blk, 0, stream>>>(
        Wq + wo, Wk + wo, Wv + wo, Wr + wo, Whi + wo, Whj + wo, Wt6);
    pack_bias_kernel<<<dim3(3), blk, 0, stream>>>(
        bq + (size_t)l * DH, bk + (size_t)l * DH, bv + (size_t)l * DH, br + (size_t)l * DH, bias768);
    pack_bt_kernel<<<dim3(1, DFF), blk, 0, stream>>>(W1 + (size_t)l * DH * DFF, W1t, DFF, DH, DH);
    pack_bt_kernel<<<dim3(2, DH), blk, 0, stream>>>(W2 + (size_t)l * DFF * DH, W2t, DH, DFF, DFF);

    // fused 6-way projection: qkvp[N][768] bf16
    gemm_bf16<<<dim3(MB, 6), blk, 0, stream>>>(
        x_bf, KIN, Wt6, KIN, bias768, qkvp, NPROJ, NN, NPROJ, KIN, 0, 1);

    // global-softmax attention + aggregation
    init_scalars<<<1, 64, 0, stream>>>(scal);
    attn_logits<<<dim3(ALB), blk, 0, stream>>>(ei, qkvp, s_e, scal);
    exp_sum<<<dim3(EE / 256), blk, 0, stream>>>(s_e, scal, scal + 1);
    aggregate_kernel<<<dim3(NN / 4), blk, 0, stream>>>(
        ei, offsets, csr, s_e, scal, qkvp, ea, h);

    // FFMLP with pre-norm residual
    ln_kernel<<<dim3(NN / 4), blk, 0, stream>>>(h, nullptr, g1 + (size_t)l * DH, be1 + (size_t)l * DH, ss, ssbf);
    gemm_bf16<<<dim3(MB, 4), blk, 0, stream>>>(
        ssbf, DH, W1t, DH, b1 + (size_t)l * DFF, ff1bf, DFF, NN, DFF, DH, 1, 1);
    gemm_bf16<<<dim3(MB, 1), blk, 0, stream>>>(
        ff1bf, DFF, W2t, DFF, b2 + (size_t)l * DH, ss2, DH, NN, DH, DFF, 0, 0);
    ln_kernel<<<dim3(NN / 4), blk, 0, stream>>>(ss, ss2, g2 + (size_t)l * DH, be2 + (size_t)l * DH, nullptr, h2bf);

    // shared linear 128 -> 1546 (writes padded bf16 x for next layer / final)
    gemm_bf16<<<dim3(MB, 13), blk, 0, stream>>>(
        h2bf, DH, lint, DH, linbp, x_bf, KIN, NN, LINNS, DH, 0, 1);
  }

  // final 1546 -> 128 + leaky_relu, fp32 out
  gemm_bf16<<<dim3(MB, 1), blk, 0, stream>>>(
      x_bf, KIN, lin2t, KIN, lin2b, out, DH, NN, DH, KIN, 2, 0);
}